// Round 5
// baseline (901.137 us; speedup 1.0000x reference)
//
#include <hip/hip_runtime.h>

typedef unsigned short u16;
typedef float f32x4 __attribute__((ext_vector_type(4)));
typedef __bf16 bf16x8 __attribute__((ext_vector_type(8)));

#define AS1 __attribute__((address_space(1)))
#define AS3 __attribute__((address_space(3)))

__device__ __forceinline__ float bf2f(u16 h) {
  return __uint_as_float(((unsigned)h) << 16);
}
__device__ __forceinline__ u16 f2bf(float f) {
  unsigned u = __float_as_uint(f);
  unsigned r = (u + 0x7FFFu + ((u >> 16) & 1u)) >> 16;
  return (u16)r;
}
__device__ __forceinline__ void gload16(const u16* g, u16* l) {
  __builtin_amdgcn_global_load_lds((const AS1 void*)g, (AS3 void*)l, 16, 0, 0);
}

// ---------------------------------------------------------------- transpose
// out[C,R] = bf16(in[R,C]^T), in fp32; R,C multiples of 32
__global__ void transpose_k(const float* __restrict__ in, u16* __restrict__ out,
                            int R, int C) {
  __shared__ u16 t[32][33];
  int c0 = blockIdx.x * 32, r0 = blockIdx.y * 32;
  int tx = threadIdx.x & 31, ty = threadIdx.x >> 5; // 32 x 8
  for (int i = 0; i < 32; i += 8)
    t[ty + i][tx] = f2bf(in[(size_t)(r0 + ty + i) * C + c0 + tx]);
  __syncthreads();
  for (int i = 0; i < 32; i += 8)
    out[(size_t)(c0 + ty + i) * R + r0 + tx] = t[tx][ty + i];
}

// pack bq|bk|bv -> bqkv[2304] fp32
__global__ void pack3_k(const float* __restrict__ a, const float* __restrict__ b,
                        const float* __restrict__ c, float* __restrict__ out) {
  int i = blockIdx.x * 256 + threadIdx.x;
  float v = (i < 768) ? a[i] : (i < 1536) ? b[i - 768] : c[i - 1536];
  out[i] = v;
}

// V columns of fused qkv [16384, 2304] -> VT [bh][96][1024]
__global__ void vtrans_k(const u16* __restrict__ qkv, u16* __restrict__ vt) {
  __shared__ u16 t[32][33];
  int bh = blockIdx.z, b = bh >> 3, h = bh & 7;
  int n0 = blockIdx.y * 32, d0 = blockIdx.x * 32;
  int tx = threadIdx.x & 31, ty = threadIdx.x >> 5;
  const u16* src = qkv + (size_t)(b * 1024) * 2304 + 1536 + h * 96;
  for (int i = 0; i < 32; i += 8)
    t[ty + i][tx] = src[(size_t)(n0 + ty + i) * 2304 + d0 + tx];
  __syncthreads();
  u16* dst = vt + ((size_t)bh * 96 + d0) * 1024 + n0;
  for (int i = 0; i < 32; i += 8)
    dst[(size_t)(ty + i) * 1024 + tx] = t[tx][ty + i];
}

// ---------------------------------------------------------------- layernorm
// fp32 x -> bf16 out; gamma/beta fp32
__global__ __launch_bounds__(256) void ln_f32_k(const float* __restrict__ x,
                                                const float* __restrict__ gamma,
                                                const float* __restrict__ beta,
                                                u16* __restrict__ out) {
  __shared__ float red[8];
  int row = blockIdx.x, t = threadIdx.x;
  const float* xr = x + (size_t)row * 768;
  float v[3], s = 0.f, s2 = 0.f;
#pragma unroll
  for (int i = 0; i < 3; i++) {
    v[i] = xr[t + i * 256];
    s += v[i]; s2 += v[i] * v[i];
  }
#pragma unroll
  for (int off = 1; off < 64; off <<= 1) {
    s += __shfl_xor(s, off, 64);
    s2 += __shfl_xor(s2, off, 64);
  }
  int w = t >> 6;
  if ((t & 63) == 0) { red[w] = s; red[4 + w] = s2; }
  __syncthreads();
  s = red[0] + red[1] + red[2] + red[3];
  s2 = red[4] + red[5] + red[6] + red[7];
  float mu = s * (1.f / 768.f);
  float var = s2 * (1.f / 768.f) - mu * mu;
  float rs = rsqrtf(var + 1e-5f);
  u16* orow = out + (size_t)row * 768;
#pragma unroll
  for (int i = 0; i < 3; i++) {
    int c = t + i * 256;
    orow[c] = f2bf((v[i] - mu) * rs * gamma[c] + beta[c]);
  }
}

// ---------------------------------------------------------------- GEMM
// EPI 0: C=bf16(A@Bt^T + bias)
// EPI 2: C=bf16(gelu(A@Bt^T + bias))
// EPI 4: C=fp32(A@Bt^T + bias + res_fp32)   (res may alias C 1:1)
// R5: fragment-major LDS layout — each 16x32 subtile stored as one
// contiguous 1KB block in exactly the wave's MFMA-read order (lane*16B),
// so every ds_read_b128 is a contiguous 1KB wave read = conflict-free.
// Staging keeps LDS linear (gload_lds constraint) and permutes the
// per-lane GLOBAL source instead (m173 pattern).
// 2-phase double-buffered K-loop: stage tile t+1 into buf^1 while
// computing tile t; ONE barrier per K-step; vmcnt drain sits after the
// full compute phase. XCD-aware block swizzle (gridDim.x % 8 == 0).
#define BM 128
#define BN 128
#define BK 64

template <int EPI>
__global__ __launch_bounds__(256, 2) void gemm_bt(
    const u16* __restrict__ A, const u16* __restrict__ Bt,
    const float* __restrict__ bias, const float* __restrict__ res,
    void* __restrict__ Cv, int M, int N, int K, int lda) {
  __shared__ u16 As[2][BM * BK];
  __shared__ u16 Bs[2][BN * BK];
  int tid = threadIdx.x, lane = tid & 63, w = tid >> 6;
  int l15 = lane & 15, quad = lane >> 4;
  int wm = (w >> 1) * 64, wn = (w & 1) * 64;
  // XCD-aware swizzle: f = HW linear block id (x fastest)
  int GX = gridDim.x;
  int f = blockIdx.y * GX + blockIdx.x;
  int mpx = GX >> 3;                     // m-tiles per XCD
  int xcd = f & 7, idx = f >> 3;
  int m0 = (xcd * mpx + (idx % mpx)) * BM;
  int n0 = (idx / mpx) * BN;
  // staging: chunk c = w*4+i stages subtile c (16 rows x 32 cols, 1KB)
  // lane covers row (c>>1)*16 + l15, cols (c&1)*32 + quad*8 .. +7
  int sr[4], sc[4];
#pragma unroll
  for (int i = 0; i < 4; i++) {
    int c = w * 4 + i;
    sr[i] = (c >> 1) * 16 + l15;
    sc[i] = (c & 1) * 32 + quad * 8;
  }
  int NT = K / BK;
  // prologue: stage tile 0
#pragma unroll
  for (int i = 0; i < 4; i++) {
    int c = w * 4 + i;
    gload16(A + (size_t)(m0 + sr[i]) * lda + sc[i], As[0] + c * 512);
    gload16(Bt + (size_t)(n0 + sr[i]) * K + sc[i], Bs[0] + c * 512);
  }
  __syncthreads();
  f32x4 acc[4][4] = {};
  for (int t = 0; t < NT; t++) {
    int cur = t & 1;
    // stage next tile into the other buffer (completion only needed at
    // the barrier below — hidden under this tile's ds_reads + MFMA)
    if (t + 1 < NT) {
      int k0 = (t + 1) * BK;
#pragma unroll
      for (int i = 0; i < 4; i++) {
        int c = w * 4 + i;
        gload16(A + (size_t)(m0 + sr[i]) * lda + k0 + sc[i], As[cur ^ 1] + c * 512);
        gload16(Bt + (size_t)(n0 + sr[i]) * K + k0 + sc[i], Bs[cur ^ 1] + c * 512);
      }
    }
    const u16* ab = As[cur];
    const u16* bb = Bs[cur];
#pragma unroll
    for (int kk = 0; kk < 2; kk++) {
      bf16x8 af[4], bfv[4];
#pragma unroll
      for (int i = 0; i < 4; i++) {
        int i2a = (w >> 1) * 4 + i;      // row-group in A tile
        int i2b = (w & 1) * 4 + i;       // row-group in B tile
        af[i] = *(const bf16x8*)(ab + (i2a * 2 + kk) * 512 + lane * 8);
        bfv[i] = *(const bf16x8*)(bb + (i2b * 2 + kk) * 512 + lane * 8);
      }
#pragma unroll
      for (int mt = 0; mt < 4; mt++)
#pragma unroll
        for (int nt = 0; nt < 4; nt++)
          acc[mt][nt] = __builtin_amdgcn_mfma_f32_16x16x32_bf16(
              af[mt], bfv[nt], acc[mt][nt], 0, 0, 0);
    }
    __syncthreads();
  }
  // epilogue: C/D layout col=lane&15, row=quad*4+reg (m89/m91-verified)
#pragma unroll
  for (int nt = 0; nt < 4; nt++) {
    int col = n0 + wn + nt * 16 + l15;
    float bv = bias[col];
#pragma unroll
    for (int mt = 0; mt < 4; mt++) {
      int row = m0 + wm + mt * 16 + quad * 4;
#pragma unroll
      for (int r = 0; r < 4; r++) {
        float v = acc[mt][nt][r] + bv;
        size_t idx2 = (size_t)(row + r) * N + col;
        if (EPI == 4) {
          v += res[idx2];
          ((float*)Cv)[idx2] = v;
        } else {
          if (EPI == 2) v = 0.5f * v * (1.0f + erff(v * 0.70710678118654752f));
          ((u16*)Cv)[idx2] = f2bf(v);
        }
      }
    }
  }
}

// ---------------------------------------------------------------- attention
// flash-style on the fused qkv buffer [16384, 2304] (q cols 0..767,
// k cols 768..1535; output written into dead v cols 1536..2303).
// vt: [bh][96][1024]. R1: padded LDS strides. R2/R3: 2-phase schedule,
// double-buffered ks/vts, wraparound reg prefetch, ONE barrier/kt.
// R4: XCD swizzle; per-lane partial li; scale folded into exp args.
#define QSS 104
#define VSS 72
#define PSS 72
#define QST 2304
__global__ __launch_bounds__(256, 2) void attn_k(u16* __restrict__ qkv,
                                                 const u16* __restrict__ vt) {
  __shared__ u16 qs[64 * QSS];
  __shared__ u16 ks[2][64 * QSS];
  __shared__ u16 vts[2][96 * VSS];
  __shared__ u16 ps[4 * 16 * PSS];
  int tid = threadIdx.x, lane = tid & 63, w = tid >> 6;
  int l15 = lane & 15, quad = lane >> 4;
  // XCD swizzle: grid (16,128); give each XCD 16 contiguous bh (all qt)
  int f = blockIdx.y * 16 + blockIdx.x;
  int xcd = f & 7, idx = f >> 3;        // idx in [0,256)
  int bh = xcd * 16 + (idx & 15);
  int qt = idx >> 4;
  int b = bh >> 3, h = bh & 7;
  const u16* qbase = qkv + (size_t)(b * 1024 + qt * 64) * QST + h * 96;
  const u16* kbase = qkv + (size_t)(b * 1024) * QST + 768 + h * 96;
  const u16* vtbase = vt + (size_t)bh * 96 * 1024;
  // per-thread staging coordinates (3 chunks each for K and VT)
  int kr[3], ko[3], vr[3], vo[3];
#pragma unroll
  for (int i = 0; i < 3; i++) {
    int c = tid + i * 256;
    kr[i] = c / 12; ko[i] = (c % 12) * 8;
    vr[i] = c >> 3; vo[i] = (c & 7) * 8;
  }
  // Q stage
#pragma unroll
  for (int i = 0; i < 3; i++)
    *(uint4*)(qs + kr[i] * QSS + ko[i]) =
        *(const uint4*)(qbase + (size_t)kr[i] * QST + ko[i]);
  // prologue: stage tile 0
  uint4 kreg[3], vreg[3];
#pragma unroll
  for (int i = 0; i < 3; i++) {
    kreg[i] = *(const uint4*)(kbase + (size_t)kr[i] * QST + ko[i]);
    vreg[i] = *(const uint4*)(vtbase + (size_t)vr[i] * 1024 + vo[i]);
  }
#pragma unroll
  for (int i = 0; i < 3; i++) {
    *(uint4*)(ks[0] + kr[i] * QSS + ko[i]) = kreg[i];
    *(uint4*)(vts[0] + vr[i] * VSS + vo[i]) = vreg[i];
  }
  __syncthreads();

  float mi[4], li[4];   // mi: RAW-domain running max; li: per-lane PARTIAL sum
#pragma unroll
  for (int r = 0; r < 4; r++) { mi[r] = -1e30f; li[r] = 0.f; }
  f32x4 oacc[6] = {};
  const float scale = 0.10206207261596577f; // 1/sqrt(96)
  for (int kt = 0; kt < 16; kt++) {
    int cur = kt & 1, nxt = cur ^ 1;
    int ktn = (kt + 1) & 15;  // wraparound: last iter re-fetches tile 0
    // issue prefetch of next tile (completion waited only at the ds_write
    // block after PV — ~2000cy of compute hides the latency)
#pragma unroll
    for (int i = 0; i < 3; i++) {
      kreg[i] = *(const uint4*)(kbase + (size_t)(ktn * 64 + kr[i]) * QST + ko[i]);
      vreg[i] = *(const uint4*)(vtbase + (size_t)vr[i] * 1024 + ktn * 64 + vo[i]);
    }
    // QK^T on current buffer
    f32x4 s[4] = {};
#pragma unroll
    for (int kk = 0; kk < 3; kk++) {
      bf16x8 a = *(const bf16x8*)(qs + (w * 16 + l15) * QSS + kk * 32 + quad * 8);
#pragma unroll
      for (int nt = 0; nt < 4; nt++) {
        bf16x8 bb =
            *(const bf16x8*)(ks[cur] + (nt * 16 + l15) * QSS + kk * 32 + quad * 8);
        s[nt] = __builtin_amdgcn_mfma_f32_16x16x32_bf16(a, bb, s[nt], 0, 0, 0);
      }
    }
    // online softmax (4 rows per lane-group via quad); raw-domain max
#pragma unroll
    for (int r = 0; r < 4; r++) {
      float sv[4], mx = -1e30f;
#pragma unroll
      for (int nt = 0; nt < 4; nt++) {
        sv[nt] = s[nt][r];
        mx = fmaxf(mx, sv[nt]);
      }
#pragma unroll
      for (int off = 1; off < 16; off <<= 1) mx = fmaxf(mx, __shfl_xor(mx, off, 16));
      float mnew = fmaxf(mi[r], mx);
      float alpha = __expf((mi[r] - mnew) * scale);
      float rs = 0.f;
#pragma unroll
      for (int nt = 0; nt < 4; nt++) {
        sv[nt] = __expf((sv[nt] - mnew) * scale);
        rs += sv[nt];
      }
      li[r] = li[r] * alpha + rs;   // per-lane partial; reduced after loop
      mi[r] = mnew;
#pragma unroll
      for (int ht = 0; ht < 6; ht++) oacc[ht][r] *= alpha;
      int prow = quad * 4 + r;
#pragma unroll
      for (int nt = 0; nt < 4; nt++)
        ps[w * 16 * PSS + prow * PSS + nt * 16 + l15] = f2bf(sv[nt]);
    }
    // ps is wave-private: order write->read within the wave, no barrier
    asm volatile("s_waitcnt lgkmcnt(0)" ::: "memory");
    // PV on current buffer
#pragma unroll
    for (int kk = 0; kk < 2; kk++) {
      bf16x8 a = *(const bf16x8*)(ps + w * 16 * PSS + l15 * PSS + kk * 32 + quad * 8);
#pragma unroll
      for (int ht = 0; ht < 6; ht++) {
        bf16x8 bb =
            *(const bf16x8*)(vts[cur] + (ht * 16 + l15) * VSS + kk * 32 + quad * 8);
        oacc[ht] = __builtin_amdgcn_mfma_f32_16x16x32_bf16(a, bb, oacc[ht], 0, 0, 0);
      }
    }
    // write prefetched tile into next buffer (freed by the barrier that
    // ended iteration kt-1), then the single per-iteration barrier
#pragma unroll
    for (int i = 0; i < 3; i++) {
      *(uint4*)(ks[nxt] + kr[i] * QSS + ko[i]) = kreg[i];
      *(uint4*)(vts[nxt] + vr[i] * VSS + vo[i]) = vreg[i];
    }
    __syncthreads();
  }
  // reduce per-lane partial li across the 16-lane row group (once)
#pragma unroll
  for (int r = 0; r < 4; r++)
#pragma unroll
    for (int off = 1; off < 16; off <<= 1) li[r] += __shfl_xor(li[r], off, 16);
  // write into dead v columns (1536..2303) of the fused buffer
  u16* obase = qkv + (size_t)(b * 1024 + qt * 64 + w * 16) * QST + 1536 + h * 96;
#pragma unroll
  for (int r = 0; r < 4; r++) {
    float inv = 1.0f / li[r];
    int row = quad * 4 + r;
#pragma unroll
    for (int ht = 0; ht < 6; ht++)
      obase[(size_t)row * QST + ht * 16 + l15] = f2bf(oacc[ht][r] * inv);
  }
}

// ---------------------------------------------------------------- launch
// d_out is FP32 (reference output dtype). y1 lives in d_out as fp32;
// final GEMM reads res=y1 and writes out 1:1-aliased (safe: each (row,col)
// is read-then-written by exactly one thread).
// ws: weights 14.2MB + bqkv 9.2KB + buf1 25.2MB + buf2 75.5MB ~= 115MB.
extern "C" void kernel_launch(void* const* d_in, const int* in_sizes, int n_in,
                              void* d_out, int out_size, void* d_ws,
                              size_t ws_size, hipStream_t stream) {
  const float* x = (const float*)d_in[0];
  const float* gamma = (const float*)d_in[1];
  const float* beta = (const float*)d_in[2];
  const float* Wq = (const float*)d_in[3];
  const float* bq = (const float*)d_in[4];
  const float* Wk = (const float*)d_in[5];
  const float* bk = (const float*)d_in[6];
  const float* Wv = (const float*)d_in[7];
  const float* bv = (const float*)d_in[8];
  const float* Wo = (const float*)d_in[9];
  const float* bo = (const float*)d_in[10];
  const float* W1 = (const float*)d_in[11];
  const float* b1 = (const float*)d_in[12];
  const float* W2 = (const float*)d_in[13];
  const float* b2 = (const float*)d_in[14];
  float* out = (float*)d_out;

  char* ws = (char*)d_ws;
  size_t off = 0;
  auto alloc = [&](size_t elems) {
    u16* p = (u16*)(ws + off);
    off += elems * sizeof(u16);
    return p;
  };
  u16* WqT = alloc(768 * 768);   // WqT|WkT|WvT adjacent = fused [2304,768]
  u16* WkT = alloc(768 * 768);
  u16* WvT = alloc(768 * 768);
  u16* WoT = alloc(768 * 768);
  u16* W1T = alloc((size_t)768 * 3072);    // [3072,768]
  u16* W2T = alloc((size_t)3072 * 768);    // [768,3072]
  float* bqkv = (float*)(ws + off); off += 2304 * sizeof(float);
  u16* buf1 = alloc((size_t)16384 * 768);   // h -> VT -> h2
  u16* buf2 = alloc((size_t)16384 * 2304);  // qkv (+attn out) -> f-chunks

  // weight transposes fp32 -> bf16 [N,K]
  transpose_k<<<dim3(24, 24), 256, 0, stream>>>(Wq, WqT, 768, 768);
  transpose_k<<<dim3(24, 24), 256, 0, stream>>>(Wk, WkT, 768, 768);
  transpose_k<<<dim3(24, 24), 256, 0, stream>>>(Wv, WvT, 768, 768);
  transpose_k<<<dim3(24, 24), 256, 0, stream>>>(Wo, WoT, 768, 768);
  transpose_k<<<dim3(96, 24), 256, 0, stream>>>(W1, W1T, 768, 3072);
  transpose_k<<<dim3(24, 96), 256, 0, stream>>>(W2, W2T, 3072, 768);
  pack3_k<<<9, 256, 0, stream>>>(bq, bk, bv, bqkv);

  // LN1: x(fp32) -> h(bf16) in buf1
  ln_f32_k<<<16384, 256, 0, stream>>>(x, gamma, beta, buf1);
  // fused QKV projection: [16384,768] @ [2304,768]^T -> buf2 [16384,2304]
  gemm_bt<0><<<dim3(128, 18), 256, 0, stream>>>(buf1, WqT, bqkv, nullptr,
                                                buf2, 16384, 2304, 768, 768);
  // V cols -> VT [bh][96][1024] into buf1 (h dead)
  vtrans_k<<<dim3(3, 32, 128), 256, 0, stream>>>(buf2, buf1);
  // attention: reads q,k cols + VT; writes attn-out into v cols of buf2
  attn_k<<<dim3(16, 128), 256, 0, stream>>>(buf2, buf1);
  // y1(fp32, in d_out) = attn_out @ Wo + bo + x  (A = v cols, lda 2304)
  gemm_bt<4><<<dim3(128, 6), 256, 0, stream>>>(buf2 + 1536, WoT, bo, x, out,
                                               16384, 768, 768, 2304);
  // h2 = LN(y1) -> buf1 (VT dead)
  ln_f32_k<<<16384, 256, 0, stream>>>(out, gamma, beta, buf1);
  // FFN in 2 M-chunks of 8192 rows; f-chunk [8192,3072] bf16 fits buf2
  for (int c = 0; c < 2; c++) {
    const u16* h2c = buf1 + (size_t)c * 8192 * 768;
    const float* y1c = out + (size_t)c * 8192 * 768;
    float* outc = out + (size_t)c * 8192 * 768;
    gemm_bt<2><<<dim3(64, 24), 256, 0, stream>>>(h2c, W1T, b1, nullptr, buf2,
                                                 8192, 3072, 768, 768);
    gemm_bt<4><<<dim3(64, 6), 256, 0, stream>>>(buf2, W2T, b2, y1c, outc,
                                                8192, 768, 3072, 3072);
  }
}

// Round 6
// 886.189 us; speedup vs baseline: 1.0169x; 1.0169x over previous
//
#include <hip/hip_runtime.h>

typedef unsigned short u16;
typedef float f32x4 __attribute__((ext_vector_type(4)));
typedef __bf16 bf16x8 __attribute__((ext_vector_type(8)));

#define AS1 __attribute__((address_space(1)))
#define AS3 __attribute__((address_space(3)))

__device__ __forceinline__ float bf2f(u16 h) {
  return __uint_as_float(((unsigned)h) << 16);
}
__device__ __forceinline__ u16 f2bf(float f) {
  unsigned u = __float_as_uint(f);
  unsigned r = (u + 0x7FFFu + ((u >> 16) & 1u)) >> 16;
  return (u16)r;
}
__device__ __forceinline__ void gload16(const u16* g, u16* l) {
  __builtin_amdgcn_global_load_lds((const AS1 void*)g, (AS3 void*)l, 16, 0, 0);
}

// ---------------------------------------------------------------- transpose
// out[C,R] = bf16(in[R,C]^T), in fp32; R,C multiples of 32
__global__ void transpose_k(const float* __restrict__ in, u16* __restrict__ out,
                            int R, int C) {
  __shared__ u16 t[32][33];
  int c0 = blockIdx.x * 32, r0 = blockIdx.y * 32;
  int tx = threadIdx.x & 31, ty = threadIdx.x >> 5; // 32 x 8
  for (int i = 0; i < 32; i += 8)
    t[ty + i][tx] = f2bf(in[(size_t)(r0 + ty + i) * C + c0 + tx]);
  __syncthreads();
  for (int i = 0; i < 32; i += 8)
    out[(size_t)(c0 + ty + i) * R + r0 + tx] = t[tx][ty + i];
}

// V(bf16) [16,1024, h*96+d] -> VT [bh][96][1024]
__global__ void vtrans_k(const u16* __restrict__ v, u16* __restrict__ vt) {
  __shared__ u16 t[32][33];
  int bh = blockIdx.z, b = bh >> 3, h = bh & 7;
  int n0 = blockIdx.y * 32, d0 = blockIdx.x * 32;
  int tx = threadIdx.x & 31, ty = threadIdx.x >> 5;
  const u16* src = v + (size_t)(b * 1024) * 768 + h * 96;
  for (int i = 0; i < 32; i += 8)
    t[ty + i][tx] = src[(size_t)(n0 + ty + i) * 768 + d0 + tx];
  __syncthreads();
  u16* dst = vt + ((size_t)bh * 96 + d0) * 1024 + n0;
  for (int i = 0; i < 32; i += 8)
    dst[(size_t)(ty + i) * 1024 + tx] = t[tx][ty + i];
}

// ---------------------------------------------------------------- layernorm
// fp32 x -> bf16 out; gamma/beta fp32
__global__ __launch_bounds__(256) void ln_f32_k(const float* __restrict__ x,
                                                const float* __restrict__ gamma,
                                                const float* __restrict__ beta,
                                                u16* __restrict__ out) {
  __shared__ float red[8];
  int row = blockIdx.x, t = threadIdx.x;
  const float* xr = x + (size_t)row * 768;
  float v[3], s = 0.f, s2 = 0.f;
#pragma unroll
  for (int i = 0; i < 3; i++) {
    v[i] = xr[t + i * 256];
    s += v[i]; s2 += v[i] * v[i];
  }
#pragma unroll
  for (int off = 1; off < 64; off <<= 1) {
    s += __shfl_xor(s, off, 64);
    s2 += __shfl_xor(s2, off, 64);
  }
  int w = t >> 6;
  if ((t & 63) == 0) { red[w] = s; red[4 + w] = s2; }
  __syncthreads();
  s = red[0] + red[1] + red[2] + red[3];
  s2 = red[4] + red[5] + red[6] + red[7];
  float mu = s * (1.f / 768.f);
  float var = s2 * (1.f / 768.f) - mu * mu;
  float rs = rsqrtf(var + 1e-5f);
  u16* orow = out + (size_t)row * 768;
#pragma unroll
  for (int i = 0; i < 3; i++) {
    int c = t + i * 256;
    orow[c] = f2bf((v[i] - mu) * rs * gamma[c] + beta[c]);
  }
}

// ---------------------------------------------------------------- GEMM
// EPI 0: C=bf16(A@Bt^T + bias)
// EPI 2: C=bf16(gelu(A@Bt^T + bias))
// EPI 4: C=fp32(A@Bt^T + bias + res_fp32)   (res may alias C 1:1)
// R5/R6: fragment-major LDS layout — each 16x32 subtile stored as one
// contiguous 1KB block in exactly the wave's MFMA-read order (lane*16B),
// so every ds_read_b128 is a contiguous 1KB wave read = conflict-free.
// Staging keeps LDS linear (gload_lds constraint) and permutes the
// per-lane GLOBAL source instead (m173 pattern).
// 2-phase double-buffered K-loop: stage tile t+1 into buf^1 while
// computing tile t; ONE barrier per K-step; vmcnt drain sits after the
// full compute phase. XCD-aware block swizzle (gridDim.x % 8 == 0).
#define BM 128
#define BN 128
#define BK 64

template <int EPI>
__global__ __launch_bounds__(256, 2) void gemm_bt(
    const u16* __restrict__ A, const u16* __restrict__ Bt,
    const float* __restrict__ bias, const float* __restrict__ res,
    void* __restrict__ Cv, int M, int N, int K, int lda) {
  __shared__ u16 As[2][BM * BK];
  __shared__ u16 Bs[2][BN * BK];
  int tid = threadIdx.x, lane = tid & 63, w = tid >> 6;
  int l15 = lane & 15, quad = lane >> 4;
  int wm = (w >> 1) * 64, wn = (w & 1) * 64;
  // XCD-aware swizzle: f = HW linear block id (x fastest)
  int GX = gridDim.x;
  int f = blockIdx.y * GX + blockIdx.x;
  int mpx = GX >> 3;                     // m-tiles per XCD
  int xcd = f & 7, idx = f >> 3;
  int m0 = (xcd * mpx + (idx % mpx)) * BM;
  int n0 = (idx / mpx) * BN;
  // staging: chunk c = w*4+i stages subtile c (16 rows x 32 cols, 1KB)
  // lane covers row (c>>1)*16 + l15, cols (c&1)*32 + quad*8 .. +7
  int sr[4], sc[4];
#pragma unroll
  for (int i = 0; i < 4; i++) {
    int c = w * 4 + i;
    sr[i] = (c >> 1) * 16 + l15;
    sc[i] = (c & 1) * 32 + quad * 8;
  }
  int NT = K / BK;
  // prologue: stage tile 0
#pragma unroll
  for (int i = 0; i < 4; i++) {
    int c = w * 4 + i;
    gload16(A + (size_t)(m0 + sr[i]) * lda + sc[i], As[0] + c * 512);
    gload16(Bt + (size_t)(n0 + sr[i]) * K + sc[i], Bs[0] + c * 512);
  }
  __syncthreads();
  f32x4 acc[4][4] = {};
  for (int t = 0; t < NT; t++) {
    int cur = t & 1;
    // stage next tile into the other buffer (completion only needed at
    // the barrier below — hidden under this tile's ds_reads + MFMA)
    if (t + 1 < NT) {
      int k0 = (t + 1) * BK;
#pragma unroll
      for (int i = 0; i < 4; i++) {
        int c = w * 4 + i;
        gload16(A + (size_t)(m0 + sr[i]) * lda + k0 + sc[i], As[cur ^ 1] + c * 512);
        gload16(Bt + (size_t)(n0 + sr[i]) * K + k0 + sc[i], Bs[cur ^ 1] + c * 512);
      }
    }
    const u16* ab = As[cur];
    const u16* bb = Bs[cur];
#pragma unroll
    for (int kk = 0; kk < 2; kk++) {
      bf16x8 af[4], bfv[4];
#pragma unroll
      for (int i = 0; i < 4; i++) {
        int i2a = (w >> 1) * 4 + i;      // row-group in A tile
        int i2b = (w & 1) * 4 + i;       // row-group in B tile
        af[i] = *(const bf16x8*)(ab + (i2a * 2 + kk) * 512 + lane * 8);
        bfv[i] = *(const bf16x8*)(bb + (i2b * 2 + kk) * 512 + lane * 8);
      }
#pragma unroll
      for (int mt = 0; mt < 4; mt++)
#pragma unroll
        for (int nt = 0; nt < 4; nt++)
          acc[mt][nt] = __builtin_amdgcn_mfma_f32_16x16x32_bf16(
              af[mt], bfv[nt], acc[mt][nt], 0, 0, 0);
    }
    __syncthreads();
  }
  // epilogue: C/D layout col=lane&15, row=quad*4+reg (m89/m91-verified)
#pragma unroll
  for (int nt = 0; nt < 4; nt++) {
    int col = n0 + wn + nt * 16 + l15;
    float bv = bias[col];
#pragma unroll
    for (int mt = 0; mt < 4; mt++) {
      int row = m0 + wm + mt * 16 + quad * 4;
#pragma unroll
      for (int r = 0; r < 4; r++) {
        float v = acc[mt][nt][r] + bv;
        size_t idx2 = (size_t)(row + r) * N + col;
        if (EPI == 4) {
          v += res[idx2];
          ((float*)Cv)[idx2] = v;
        } else {
          if (EPI == 2) v = 0.5f * v * (1.0f + erff(v * 0.70710678118654752f));
          ((u16*)Cv)[idx2] = f2bf(v);
        }
      }
    }
  }
}

// ---------------------------------------------------------------- attention
// flash-style; q,k: [16384,768] bf16 head-sliced; vt: [bh][96][1024]; o same
// (compact buffers — R5's fused-buffer strided output caused 8x write
// amplification via partial-line RFO; reverted).
// R1: padded LDS strides. R2/R3: 2-phase schedule, double-buffered ks/vts,
// wraparound reg prefetch, ONE barrier/kt. R4: XCD swizzle; per-lane
// partial li; scale folded into exp args.
#define QSS 104
#define VSS 72
#define PSS 72
__global__ __launch_bounds__(256, 2) void attn_k(const u16* __restrict__ q,
                                                 const u16* __restrict__ k,
                                                 const u16* __restrict__ vt,
                                                 u16* __restrict__ o) {
  __shared__ u16 qs[64 * QSS];
  __shared__ u16 ks[2][64 * QSS];
  __shared__ u16 vts[2][96 * VSS];
  __shared__ u16 ps[4 * 16 * PSS];
  int tid = threadIdx.x, lane = tid & 63, w = tid >> 6;
  int l15 = lane & 15, quad = lane >> 4;
  // XCD swizzle: grid (16,128); give each XCD 16 contiguous bh (all qt)
  int f = blockIdx.y * 16 + blockIdx.x;
  int xcd = f & 7, idx = f >> 3;        // idx in [0,256)
  int bh = xcd * 16 + (idx & 15);
  int qt = idx >> 4;
  int b = bh >> 3, h = bh & 7;
  const u16* qbase = q + (size_t)(b * 1024 + qt * 64) * 768 + h * 96;
  const u16* kbase = k + (size_t)(b * 1024) * 768 + h * 96;
  const u16* vtbase = vt + (size_t)bh * 96 * 1024;
  // per-thread staging coordinates (3 chunks each for K and VT)
  int kr[3], ko[3], vr[3], vo[3];
#pragma unroll
  for (int i = 0; i < 3; i++) {
    int c = tid + i * 256;
    kr[i] = c / 12; ko[i] = (c % 12) * 8;
    vr[i] = c >> 3; vo[i] = (c & 7) * 8;
  }
  // Q stage
#pragma unroll
  for (int i = 0; i < 3; i++)
    *(uint4*)(qs + kr[i] * QSS + ko[i]) =
        *(const uint4*)(qbase + (size_t)kr[i] * 768 + ko[i]);
  // prologue: stage tile 0
  uint4 kreg[3], vreg[3];
#pragma unroll
  for (int i = 0; i < 3; i++) {
    kreg[i] = *(const uint4*)(kbase + (size_t)kr[i] * 768 + ko[i]);
    vreg[i] = *(const uint4*)(vtbase + (size_t)vr[i] * 1024 + vo[i]);
  }
#pragma unroll
  for (int i = 0; i < 3; i++) {
    *(uint4*)(ks[0] + kr[i] * QSS + ko[i]) = kreg[i];
    *(uint4*)(vts[0] + vr[i] * VSS + vo[i]) = vreg[i];
  }
  __syncthreads();

  float mi[4], li[4];   // mi: RAW-domain running max; li: per-lane PARTIAL sum
#pragma unroll
  for (int r = 0; r < 4; r++) { mi[r] = -1e30f; li[r] = 0.f; }
  f32x4 oacc[6] = {};
  const float scale = 0.10206207261596577f; // 1/sqrt(96)
  for (int kt = 0; kt < 16; kt++) {
    int cur = kt & 1, nxt = cur ^ 1;
    int ktn = (kt + 1) & 15;  // wraparound: last iter re-fetches tile 0
    // issue prefetch of next tile (completion waited only at the ds_write
    // block after PV — ~2000cy of compute hides the latency)
#pragma unroll
    for (int i = 0; i < 3; i++) {
      kreg[i] = *(const uint4*)(kbase + (size_t)(ktn * 64 + kr[i]) * 768 + ko[i]);
      vreg[i] = *(const uint4*)(vtbase + (size_t)vr[i] * 1024 + ktn * 64 + vo[i]);
    }
    // QK^T on current buffer
    f32x4 s[4] = {};
#pragma unroll
    for (int kk = 0; kk < 3; kk++) {
      bf16x8 a = *(const bf16x8*)(qs + (w * 16 + l15) * QSS + kk * 32 + quad * 8);
#pragma unroll
      for (int nt = 0; nt < 4; nt++) {
        bf16x8 bb =
            *(const bf16x8*)(ks[cur] + (nt * 16 + l15) * QSS + kk * 32 + quad * 8);
        s[nt] = __builtin_amdgcn_mfma_f32_16x16x32_bf16(a, bb, s[nt], 0, 0, 0);
      }
    }
    // online softmax (4 rows per lane-group via quad); raw-domain max
#pragma unroll
    for (int r = 0; r < 4; r++) {
      float sv[4], mx = -1e30f;
#pragma unroll
      for (int nt = 0; nt < 4; nt++) {
        sv[nt] = s[nt][r];
        mx = fmaxf(mx, sv[nt]);
      }
#pragma unroll
      for (int off = 1; off < 16; off <<= 1) mx = fmaxf(mx, __shfl_xor(mx, off, 16));
      float mnew = fmaxf(mi[r], mx);
      float alpha = __expf((mi[r] - mnew) * scale);
      float rs = 0.f;
#pragma unroll
      for (int nt = 0; nt < 4; nt++) {
        sv[nt] = __expf((sv[nt] - mnew) * scale);
        rs += sv[nt];
      }
      li[r] = li[r] * alpha + rs;   // per-lane partial; reduced after loop
      mi[r] = mnew;
#pragma unroll
      for (int ht = 0; ht < 6; ht++) oacc[ht][r] *= alpha;
      int prow = quad * 4 + r;
#pragma unroll
      for (int nt = 0; nt < 4; nt++)
        ps[w * 16 * PSS + prow * PSS + nt * 16 + l15] = f2bf(sv[nt]);
    }
    // ps is wave-private: order write->read within the wave, no barrier
    asm volatile("s_waitcnt lgkmcnt(0)" ::: "memory");
    // PV on current buffer
#pragma unroll
    for (int kk = 0; kk < 2; kk++) {
      bf16x8 a = *(const bf16x8*)(ps + w * 16 * PSS + l15 * PSS + kk * 32 + quad * 8);
#pragma unroll
      for (int ht = 0; ht < 6; ht++) {
        bf16x8 bb =
            *(const bf16x8*)(vts[cur] + (ht * 16 + l15) * VSS + kk * 32 + quad * 8);
        oacc[ht] = __builtin_amdgcn_mfma_f32_16x16x32_bf16(a, bb, oacc[ht], 0, 0, 0);
      }
    }
    // write prefetched tile into next buffer (freed by the barrier that
    // ended iteration kt-1), then the single per-iteration barrier
#pragma unroll
    for (int i = 0; i < 3; i++) {
      *(uint4*)(ks[nxt] + kr[i] * QSS + ko[i]) = kreg[i];
      *(uint4*)(vts[nxt] + vr[i] * VSS + vo[i]) = vreg[i];
    }
    __syncthreads();
  }
  // reduce per-lane partial li across the 16-lane row group (once)
#pragma unroll
  for (int r = 0; r < 4; r++)
#pragma unroll
    for (int off = 1; off < 16; off <<= 1) li[r] += __shfl_xor(li[r], off, 16);
  u16* obase = o + (size_t)(b * 1024 + qt * 64 + w * 16) * 768 + h * 96;
#pragma unroll
  for (int r = 0; r < 4; r++) {
    float inv = 1.0f / li[r];
    int row = quad * 4 + r;
#pragma unroll
    for (int ht = 0; ht < 6; ht++)
      obase[(size_t)row * 768 + ht * 16 + l15] = f2bf(oacc[ht][r] * inv);
  }
}

// ---------------------------------------------------------------- launch
// d_out is FP32 (reference output dtype). y1 lives in d_out as fp32;
// final GEMM reads res=y1 and writes out 1:1-aliased (safe: each (row,col)
// is read-then-written by exactly one thread).
// ws: weights 14.2MB + 4 x 25.2MB bf16 buffers = 115MB (R2-proven safe).
// FFN f-chunk [8192,3072] (50.3MB) lives in hb+qb (adjacent, dead there).
extern "C" void kernel_launch(void* const* d_in, const int* in_sizes, int n_in,
                              void* d_out, int out_size, void* d_ws,
                              size_t ws_size, hipStream_t stream) {
  const float* x = (const float*)d_in[0];
  const float* gamma = (const float*)d_in[1];
  const float* beta = (const float*)d_in[2];
  const float* Wq = (const float*)d_in[3];
  const float* bq = (const float*)d_in[4];
  const float* Wk = (const float*)d_in[5];
  const float* bk = (const float*)d_in[6];
  const float* Wv = (const float*)d_in[7];
  const float* bv = (const float*)d_in[8];
  const float* Wo = (const float*)d_in[9];
  const float* bo = (const float*)d_in[10];
  const float* W1 = (const float*)d_in[11];
  const float* b1 = (const float*)d_in[12];
  const float* W2 = (const float*)d_in[13];
  const float* b2 = (const float*)d_in[14];
  float* out = (float*)d_out;

  char* ws = (char*)d_ws;
  size_t off = 0;
  auto alloc = [&](size_t elems) {
    u16* p = (u16*)(ws + off);
    off += elems * sizeof(u16);
    return p;
  };
  u16* WqT = alloc(768 * 768);
  u16* WkT = alloc(768 * 768);
  u16* WvT = alloc(768 * 768);
  u16* WoT = alloc(768 * 768);
  u16* W1T = alloc((size_t)768 * 3072);    // [3072,768]
  u16* W2T = alloc((size_t)3072 * 768);    // [768,3072]
  u16* hb = alloc((size_t)16384 * 768);    // h -> VT -> f-chunk(lo)
  u16* qb = alloc((size_t)16384 * 768);    // q -> f-chunk(hi)
  u16* kb = alloc((size_t)16384 * 768);    // k -> h2
  u16* vb = alloc((size_t)16384 * 768);    // v -> attn_out

  // weight transposes fp32 -> bf16 [N,K]
  transpose_k<<<dim3(24, 24), 256, 0, stream>>>(Wq, WqT, 768, 768);
  transpose_k<<<dim3(24, 24), 256, 0, stream>>>(Wk, WkT, 768, 768);
  transpose_k<<<dim3(24, 24), 256, 0, stream>>>(Wv, WvT, 768, 768);
  transpose_k<<<dim3(24, 24), 256, 0, stream>>>(Wo, WoT, 768, 768);
  transpose_k<<<dim3(96, 24), 256, 0, stream>>>(W1, W1T, 768, 3072);
  transpose_k<<<dim3(24, 96), 256, 0, stream>>>(W2, W2T, 3072, 768);

  // LN1: x(fp32) -> h(bf16)
  ln_f32_k<<<16384, 256, 0, stream>>>(x, gamma, beta, hb);
  // QKV projections (bf16)
  gemm_bt<0><<<dim3(128, 6), 256, 0, stream>>>(hb, WqT, bq, nullptr, qb,
                                               16384, 768, 768, 768);
  gemm_bt<0><<<dim3(128, 6), 256, 0, stream>>>(hb, WkT, bk, nullptr, kb,
                                               16384, 768, 768, 768);
  gemm_bt<0><<<dim3(128, 6), 256, 0, stream>>>(hb, WvT, bv, nullptr, vb,
                                               16384, 768, 768, 768);
  // V -> VT [bh][96][1024] into hb (h dead)
  vtrans_k<<<dim3(3, 32, 128), 256, 0, stream>>>(vb, hb);
  // attention -> vb (v dead after vtrans)
  attn_k<<<dim3(16, 128), 256, 0, stream>>>(qb, kb, hb, vb);
  // y1(fp32, in d_out) = attn @ Wo + bo + x
  gemm_bt<4><<<dim3(128, 6), 256, 0, stream>>>(vb, WoT, bo, x, out,
                                               16384, 768, 768, 768);
  // h2 = LN(y1) -> kb (k dead)
  ln_f32_k<<<16384, 256, 0, stream>>>(out, gamma, beta, kb);
  // FFN in 2 M-chunks of 8192 rows; f-chunk [8192,3072] bf16 (50.3MB)
  // fits the adjacent hb+qb region (VT and q both dead now)
  u16* fbuf = hb;
  for (int c = 0; c < 2; c++) {
    const u16* h2c = kb + (size_t)c * 8192 * 768;
    const float* y1c = out + (size_t)c * 8192 * 768;
    float* outc = out + (size_t)c * 8192 * 768;
    gemm_bt<2><<<dim3(64, 24), 256, 0, stream>>>(h2c, W1T, b1, nullptr, fbuf,
                                                 8192, 3072, 768, 768);
    gemm_bt<4><<<dim3(64, 6), 256, 0, stream>>>(fbuf, W2T, b2, y1c, outc,
                                                8192, 768, 3072, 3072);
  }
}

// Round 7
// 864.207 us; speedup vs baseline: 1.0427x; 1.0254x over previous
//
#include <hip/hip_runtime.h>

typedef unsigned short u16;
typedef float f32x4 __attribute__((ext_vector_type(4)));
typedef __bf16 bf16x8 __attribute__((ext_vector_type(8)));

#define AS1 __attribute__((address_space(1)))
#define AS3 __attribute__((address_space(3)))

__device__ __forceinline__ float bf2f(u16 h) {
  return __uint_as_float(((unsigned)h) << 16);
}
__device__ __forceinline__ u16 f2bf(float f) {
  unsigned u = __float_as_uint(f);
  unsigned r = (u + 0x7FFFu + ((u >> 16) & 1u)) >> 16;
  return (u16)r;
}
__device__ __forceinline__ void gload16(const u16* g, u16* l) {
  __builtin_amdgcn_global_load_lds((const AS1 void*)g, (AS3 void*)l, 16, 0, 0);
}

// ---------------------------------------------------------------- transpose
// out[C,R] = bf16(in[R,C]^T), in fp32; R,C multiples of 32
__global__ void transpose_k(const float* __restrict__ in, u16* __restrict__ out,
                            int R, int C) {
  __shared__ u16 t[32][33];
  int c0 = blockIdx.x * 32, r0 = blockIdx.y * 32;
  int tx = threadIdx.x & 31, ty = threadIdx.x >> 5; // 32 x 8
  for (int i = 0; i < 32; i += 8)
    t[ty + i][tx] = f2bf(in[(size_t)(r0 + ty + i) * C + c0 + tx]);
  __syncthreads();
  for (int i = 0; i < 32; i += 8)
    out[(size_t)(c0 + ty + i) * R + r0 + tx] = t[tx][ty + i];
}

// V(bf16) [16,1024, h*96+d] -> VT [bh][96][1024]
__global__ void vtrans_k(const u16* __restrict__ v, u16* __restrict__ vt) {
  __shared__ u16 t[32][33];
  int bh = blockIdx.z, b = bh >> 3, h = bh & 7;
  int n0 = blockIdx.y * 32, d0 = blockIdx.x * 32;
  int tx = threadIdx.x & 31, ty = threadIdx.x >> 5;
  const u16* src = v + (size_t)(b * 1024) * 768 + h * 96;
  for (int i = 0; i < 32; i += 8)
    t[ty + i][tx] = src[(size_t)(n0 + ty + i) * 768 + d0 + tx];
  __syncthreads();
  u16* dst = vt + ((size_t)bh * 96 + d0) * 1024 + n0;
  for (int i = 0; i < 32; i += 8)
    dst[(size_t)(ty + i) * 1024 + tx] = t[tx][ty + i];
}

// ---------------------------------------------------------------- layernorm
// fp32 x -> bf16 out; gamma/beta fp32
__global__ __launch_bounds__(256) void ln_f32_k(const float* __restrict__ x,
                                                const float* __restrict__ gamma,
                                                const float* __restrict__ beta,
                                                u16* __restrict__ out) {
  __shared__ float red[8];
  int row = blockIdx.x, t = threadIdx.x;
  const float* xr = x + (size_t)row * 768;
  float v[3], s = 0.f, s2 = 0.f;
#pragma unroll
  for (int i = 0; i < 3; i++) {
    v[i] = xr[t + i * 256];
    s += v[i]; s2 += v[i] * v[i];
  }
#pragma unroll
  for (int off = 1; off < 64; off <<= 1) {
    s += __shfl_xor(s, off, 64);
    s2 += __shfl_xor(s2, off, 64);
  }
  int w = t >> 6;
  if ((t & 63) == 0) { red[w] = s; red[4 + w] = s2; }
  __syncthreads();
  s = red[0] + red[1] + red[2] + red[3];
  s2 = red[4] + red[5] + red[6] + red[7];
  float mu = s * (1.f / 768.f);
  float var = s2 * (1.f / 768.f) - mu * mu;
  float rs = rsqrtf(var + 1e-5f);
  u16* orow = out + (size_t)row * 768;
#pragma unroll
  for (int i = 0; i < 3; i++) {
    int c = t + i * 256;
    orow[c] = f2bf((v[i] - mu) * rs * gamma[c] + beta[c]);
  }
}

// ---------------------------------------------------------------- GEMM
// EPI 0: C=bf16(A@Bt^T + bias)
// EPI 2: C=bf16(gelu(A@Bt^T + bias))
// EPI 4: C=fp32(A@Bt^T + bias + res_fp32)   (res may alias C 1:1)
// R7: BK=32 double-buffer = 32 KB LDS -> 4 blocks/CU (R6's 64 KB halved
// occupancy — m132 lesson). Fragment-major LDS subtiles (contiguous 1KB
// wave reads, conflict-free; global source pre-permuted per m173).
// COUNTED vmcnt (T4): per iter {STAGE(next); vmcnt(4); bar; ds_read+MFMA;
// bar} — just-issued loads stay in flight across both barriers; only the
// previous iteration's loads are waited. Raw s_barrier (no vmcnt(0) drain
// in loop). XCD-aware block swizzle (gridDim.x % 8 == 0).
#define BM 128
#define BN 128
#define BK 32

template <int EPI>
__global__ __launch_bounds__(256, 4) void gemm_bt(
    const u16* __restrict__ A, const u16* __restrict__ Bt,
    const float* __restrict__ bias, const float* __restrict__ res,
    void* __restrict__ Cv, int M, int N, int K, int lda) {
  __shared__ u16 As[2][BM * BK];
  __shared__ u16 Bs[2][BN * BK];
  int tid = threadIdx.x, lane = tid & 63, w = tid >> 6;
  int l15 = lane & 15, quad = lane >> 4;
  int wm = (w >> 1) * 64, wn = (w & 1) * 64;
  // XCD-aware swizzle: f = HW linear block id (x fastest)
  int GX = gridDim.x;
  int f = blockIdx.y * GX + blockIdx.x;
  int mpx = GX >> 3;                     // m-tiles per XCD
  int xcd = f & 7, idx = f >> 3;
  int m0 = (xcd * mpx + (idx % mpx)) * BM;
  int n0 = (idx / mpx) * BN;
  // staging: chunk c = w*2+i is subtile c (rows c*16..+15, cols 0..31, 1KB)
  // lane covers row c*16 + l15, cols quad*8..+7 (matches MFMA read order)
  int NT = K / BK;
  // prologue: stage tile 0 (4 gloads/thread)
#pragma unroll
  for (int i = 0; i < 2; i++) {
    int c = w * 2 + i;
    int r = c * 16 + l15, col = quad * 8;
    gload16(A + (size_t)(m0 + r) * lda + col, As[0] + c * 512);
    gload16(Bt + (size_t)(n0 + r) * K + col, Bs[0] + c * 512);
  }
  f32x4 acc[4][4] = {};
  for (int t = 0; t < NT; t++) {
    int cur = t & 1;
    // barrier 1: everyone finished reading As/Bs[cur^1] (prev iter)
    __builtin_amdgcn_s_barrier();
    int k0 = (t + 1 < NT) ? (t + 1) * BK : 0;  // wraparound: harmless restage
#pragma unroll
    for (int i = 0; i < 2; i++) {
      int c = w * 2 + i;
      int r = c * 16 + l15, col = quad * 8;
      gload16(A + (size_t)(m0 + r) * lda + k0 + col, As[cur ^ 1] + c * 512);
      gload16(Bt + (size_t)(n0 + r) * K + k0 + col, Bs[cur ^ 1] + c * 512);
    }
    // wait ONLY the previous iteration's 4 loads (into cur); keep ours flying
    asm volatile("s_waitcnt vmcnt(4)" ::: "memory");
    // barrier 2: cur tile ready for every thread
    __builtin_amdgcn_s_barrier();
    const u16* ab = As[cur];
    const u16* bb = Bs[cur];
    bf16x8 af[4], bfv[4];
#pragma unroll
    for (int i = 0; i < 4; i++) {
      af[i] = *(const bf16x8*)(ab + ((w >> 1) * 4 + i) * 512 + lane * 8);
      bfv[i] = *(const bf16x8*)(bb + ((w & 1) * 4 + i) * 512 + lane * 8);
    }
#pragma unroll
    for (int mt = 0; mt < 4; mt++)
#pragma unroll
      for (int nt = 0; nt < 4; nt++)
        acc[mt][nt] = __builtin_amdgcn_mfma_f32_16x16x32_bf16(
            af[mt], bfv[nt], acc[mt][nt], 0, 0, 0);
  }
  // drain the dangling wraparound prefetch before LDS goes out of scope
  asm volatile("s_waitcnt vmcnt(0)" ::: "memory");
  // epilogue: C/D layout col=lane&15, row=quad*4+reg (m89/m91-verified)
#pragma unroll
  for (int nt = 0; nt < 4; nt++) {
    int col = n0 + wn + nt * 16 + l15;
    float bv = bias[col];
#pragma unroll
    for (int mt = 0; mt < 4; mt++) {
      int row = m0 + wm + mt * 16 + quad * 4;
#pragma unroll
      for (int r = 0; r < 4; r++) {
        float v = acc[mt][nt][r] + bv;
        size_t idx2 = (size_t)(row + r) * N + col;
        if (EPI == 4) {
          v += res[idx2];
          ((float*)Cv)[idx2] = v;
        } else {
          if (EPI == 2) v = 0.5f * v * (1.0f + erff(v * 0.70710678118654752f));
          ((u16*)Cv)[idx2] = f2bf(v);
        }
      }
    }
  }
}

// ---------------------------------------------------------------- attention
// flash-style; q,k: [16384,768] bf16 head-sliced; vt: [bh][96][1024]; o same
// (compact buffers — R5's fused-buffer strided output caused 8x write
// amplification via partial-line RFO; reverted).
// R1: padded LDS strides. R2/R3: 2-phase schedule, double-buffered ks/vts,
// wraparound reg prefetch, ONE barrier/kt. R4: XCD swizzle; per-lane
// partial li; scale folded into exp args.
#define QSS 104
#define VSS 72
#define PSS 72
__global__ __launch_bounds__(256, 2) void attn_k(const u16* __restrict__ q,
                                                 const u16* __restrict__ k,
                                                 const u16* __restrict__ vt,
                                                 u16* __restrict__ o) {
  __shared__ u16 qs[64 * QSS];
  __shared__ u16 ks[2][64 * QSS];
  __shared__ u16 vts[2][96 * VSS];
  __shared__ u16 ps[4 * 16 * PSS];
  int tid = threadIdx.x, lane = tid & 63, w = tid >> 6;
  int l15 = lane & 15, quad = lane >> 4;
  // XCD swizzle: grid (16,128); give each XCD 16 contiguous bh (all qt)
  int f = blockIdx.y * 16 + blockIdx.x;
  int xcd = f & 7, idx = f >> 3;        // idx in [0,256)
  int bh = xcd * 16 + (idx & 15);
  int qt = idx >> 4;
  int b = bh >> 3, h = bh & 7;
  const u16* qbase = q + (size_t)(b * 1024 + qt * 64) * 768 + h * 96;
  const u16* kbase = k + (size_t)(b * 1024) * 768 + h * 96;
  const u16* vtbase = vt + (size_t)bh * 96 * 1024;
  // per-thread staging coordinates (3 chunks each for K and VT)
  int kr[3], ko[3], vr[3], vo[3];
#pragma unroll
  for (int i = 0; i < 3; i++) {
    int c = tid + i * 256;
    kr[i] = c / 12; ko[i] = (c % 12) * 8;
    vr[i] = c >> 3; vo[i] = (c & 7) * 8;
  }
  // Q stage
#pragma unroll
  for (int i = 0; i < 3; i++)
    *(uint4*)(qs + kr[i] * QSS + ko[i]) =
        *(const uint4*)(qbase + (size_t)kr[i] * 768 + ko[i]);
  // prologue: stage tile 0
  uint4 kreg[3], vreg[3];
#pragma unroll
  for (int i = 0; i < 3; i++) {
    kreg[i] = *(const uint4*)(kbase + (size_t)kr[i] * 768 + ko[i]);
    vreg[i] = *(const uint4*)(vtbase + (size_t)vr[i] * 1024 + vo[i]);
  }
#pragma unroll
  for (int i = 0; i < 3; i++) {
    *(uint4*)(ks[0] + kr[i] * QSS + ko[i]) = kreg[i];
    *(uint4*)(vts[0] + vr[i] * VSS + vo[i]) = vreg[i];
  }
  __syncthreads();

  float mi[4], li[4];   // mi: RAW-domain running max; li: per-lane PARTIAL sum
#pragma unroll
  for (int r = 0; r < 4; r++) { mi[r] = -1e30f; li[r] = 0.f; }
  f32x4 oacc[6] = {};
  const float scale = 0.10206207261596577f; // 1/sqrt(96)
  for (int kt = 0; kt < 16; kt++) {
    int cur = kt & 1, nxt = cur ^ 1;
    int ktn = (kt + 1) & 15;  // wraparound: last iter re-fetches tile 0
    // issue prefetch of next tile (completion waited only at the ds_write
    // block after PV — ~2000cy of compute hides the latency)
#pragma unroll
    for (int i = 0; i < 3; i++) {
      kreg[i] = *(const uint4*)(kbase + (size_t)(ktn * 64 + kr[i]) * 768 + ko[i]);
      vreg[i] = *(const uint4*)(vtbase + (size_t)vr[i] * 1024 + ktn * 64 + vo[i]);
    }
    // QK^T on current buffer
    f32x4 s[4] = {};
#pragma unroll
    for (int kk = 0; kk < 3; kk++) {
      bf16x8 a = *(const bf16x8*)(qs + (w * 16 + l15) * QSS + kk * 32 + quad * 8);
#pragma unroll
      for (int nt = 0; nt < 4; nt++) {
        bf16x8 bb =
            *(const bf16x8*)(ks[cur] + (nt * 16 + l15) * QSS + kk * 32 + quad * 8);
        s[nt] = __builtin_amdgcn_mfma_f32_16x16x32_bf16(a, bb, s[nt], 0, 0, 0);
      }
    }
    // online softmax (4 rows per lane-group via quad); raw-domain max
#pragma unroll
    for (int r = 0; r < 4; r++) {
      float sv[4], mx = -1e30f;
#pragma unroll
      for (int nt = 0; nt < 4; nt++) {
        sv[nt] = s[nt][r];
        mx = fmaxf(mx, sv[nt]);
      }
#pragma unroll
      for (int off = 1; off < 16; off <<= 1) mx = fmaxf(mx, __shfl_xor(mx, off, 16));
      float mnew = fmaxf(mi[r], mx);
      float alpha = __expf((mi[r] - mnew) * scale);
      float rs = 0.f;
#pragma unroll
      for (int nt = 0; nt < 4; nt++) {
        sv[nt] = __expf((sv[nt] - mnew) * scale);
        rs += sv[nt];
      }
      li[r] = li[r] * alpha + rs;   // per-lane partial; reduced after loop
      mi[r] = mnew;
#pragma unroll
      for (int ht = 0; ht < 6; ht++) oacc[ht][r] *= alpha;
      int prow = quad * 4 + r;
#pragma unroll
      for (int nt = 0; nt < 4; nt++)
        ps[w * 16 * PSS + prow * PSS + nt * 16 + l15] = f2bf(sv[nt]);
    }
    // ps is wave-private: order write->read within the wave, no barrier
    asm volatile("s_waitcnt lgkmcnt(0)" ::: "memory");
    // PV on current buffer
#pragma unroll
    for (int kk = 0; kk < 2; kk++) {
      bf16x8 a = *(const bf16x8*)(ps + w * 16 * PSS + l15 * PSS + kk * 32 + quad * 8);
#pragma unroll
      for (int ht = 0; ht < 6; ht++) {
        bf16x8 bb =
            *(const bf16x8*)(vts[cur] + (ht * 16 + l15) * VSS + kk * 32 + quad * 8);
        oacc[ht] = __builtin_amdgcn_mfma_f32_16x16x32_bf16(a, bb, oacc[ht], 0, 0, 0);
      }
    }
    // write prefetched tile into next buffer (freed by the barrier that
    // ended iteration kt-1), then the single per-iteration barrier
#pragma unroll
    for (int i = 0; i < 3; i++) {
      *(uint4*)(ks[nxt] + kr[i] * QSS + ko[i]) = kreg[i];
      *(uint4*)(vts[nxt] + vr[i] * VSS + vo[i]) = vreg[i];
    }
    __syncthreads();
  }
  // reduce per-lane partial li across the 16-lane row group (once)
#pragma unroll
  for (int r = 0; r < 4; r++)
#pragma unroll
    for (int off = 1; off < 16; off <<= 1) li[r] += __shfl_xor(li[r], off, 16);
  u16* obase = o + (size_t)(b * 1024 + qt * 64 + w * 16) * 768 + h * 96;
#pragma unroll
  for (int r = 0; r < 4; r++) {
    float inv = 1.0f / li[r];
    int row = quad * 4 + r;
#pragma unroll
    for (int ht = 0; ht < 6; ht++)
      obase[(size_t)row * 768 + ht * 16 + l15] = f2bf(oacc[ht][r] * inv);
  }
}

// ---------------------------------------------------------------- launch
// d_out is FP32 (reference output dtype). y1 lives in d_out as fp32;
// final GEMM reads res=y1 and writes out 1:1-aliased (safe: each (row,col)
// is read-then-written by exactly one thread).
// ws: weights 14.2MB + 4 x 25.2MB bf16 buffers = 115MB (R2-proven safe).
// FFN f-chunk [8192,3072] (50.3MB) lives in hb+qb (adjacent, dead there).
extern "C" void kernel_launch(void* const* d_in, const int* in_sizes, int n_in,
                              void* d_out, int out_size, void* d_ws,
                              size_t ws_size, hipStream_t stream) {
  const float* x = (const float*)d_in[0];
  const float* gamma = (const float*)d_in[1];
  const float* beta = (const float*)d_in[2];
  const float* Wq = (const float*)d_in[3];
  const float* bq = (const float*)d_in[4];
  const float* Wk = (const float*)d_in[5];
  const float* bk = (const float*)d_in[6];
  const float* Wv = (const float*)d_in[7];
  const float* bv = (const float*)d_in[8];
  const float* Wo = (const float*)d_in[9];
  const float* bo = (const float*)d_in[10];
  const float* W1 = (const float*)d_in[11];
  const float* b1 = (const float*)d_in[12];
  const float* W2 = (const float*)d_in[13];
  const float* b2 = (const float*)d_in[14];
  float* out = (float*)d_out;

  char* ws = (char*)d_ws;
  size_t off = 0;
  auto alloc = [&](size_t elems) {
    u16* p = (u16*)(ws + off);
    off += elems * sizeof(u16);
    return p;
  };
  u16* WqT = alloc(768 * 768);
  u16* WkT = alloc(768 * 768);
  u16* WvT = alloc(768 * 768);
  u16* WoT = alloc(768 * 768);
  u16* W1T = alloc((size_t)768 * 3072);    // [3072,768]
  u16* W2T = alloc((size_t)3072 * 768);    // [768,3072]
  u16* hb = alloc((size_t)16384 * 768);    // h -> VT -> f-chunk(lo)
  u16* qb = alloc((size_t)16384 * 768);    // q -> f-chunk(hi)
  u16* kb = alloc((size_t)16384 * 768);    // k -> h2
  u16* vb = alloc((size_t)16384 * 768);    // v -> attn_out

  // weight transposes fp32 -> bf16 [N,K]
  transpose_k<<<dim3(24, 24), 256, 0, stream>>>(Wq, WqT, 768, 768);
  transpose_k<<<dim3(24, 24), 256, 0, stream>>>(Wk, WkT, 768, 768);
  transpose_k<<<dim3(24, 24), 256, 0, stream>>>(Wv, WvT, 768, 768);
  transpose_k<<<dim3(24, 24), 256, 0, stream>>>(Wo, WoT, 768, 768);
  transpose_k<<<dim3(96, 24), 256, 0, stream>>>(W1, W1T, 768, 3072);
  transpose_k<<<dim3(24, 96), 256, 0, stream>>>(W2, W2T, 3072, 768);

  // LN1: x(fp32) -> h(bf16)
  ln_f32_k<<<16384, 256, 0, stream>>>(x, gamma, beta, hb);
  // QKV projections (bf16)
  gemm_bt<0><<<dim3(128, 6), 256, 0, stream>>>(hb, WqT, bq, nullptr, qb,
                                               16384, 768, 768, 768);
  gemm_bt<0><<<dim3(128, 6), 256, 0, stream>>>(hb, WkT, bk, nullptr, kb,
                                               16384, 768, 768, 768);
  gemm_bt<0><<<dim3(128, 6), 256, 0, stream>>>(hb, WvT, bv, nullptr, vb,
                                               16384, 768, 768, 768);
  // V -> VT [bh][96][1024] into hb (h dead)
  vtrans_k<<<dim3(3, 32, 128), 256, 0, stream>>>(vb, hb);
  // attention -> vb (v dead after vtrans)
  attn_k<<<dim3(16, 128), 256, 0, stream>>>(qb, kb, hb, vb);
  // y1(fp32, in d_out) = attn @ Wo + bo + x
  gemm_bt<4><<<dim3(128, 6), 256, 0, stream>>>(vb, WoT, bo, x, out,
                                               16384, 768, 768, 768);
  // h2 = LN(y1) -> kb (k dead)
  ln_f32_k<<<16384, 256, 0, stream>>>(out, gamma, beta, kb);
  // FFN in 2 M-chunks of 8192 rows; f-chunk [8192,3072] bf16 (50.3MB)
  // fits the adjacent hb+qb region (VT and q both dead now)
  u16* fbuf = hb;
  for (int c = 0; c < 2; c++) {
    const u16* h2c = kb + (size_t)c * 8192 * 768;
    const float* y1c = out + (size_t)c * 8192 * 768;
    float* outc = out + (size_t)c * 8192 * 768;
    gemm_bt<2><<<dim3(64, 24), 256, 0, stream>>>(h2c, W1T, b1, nullptr, fbuf,
                                                 8192, 3072, 768, 768);
    gemm_bt<4><<<dim3(64, 6), 256, 0, stream>>>(fbuf, W2T, b2, y1c, outc,
                                                8192, 768, 3072, 3072);
  }
}

// Round 8
// 857.845 us; speedup vs baseline: 1.0505x; 1.0074x over previous
//
#include <hip/hip_runtime.h>

typedef unsigned short u16;
typedef float f32x4 __attribute__((ext_vector_type(4)));
typedef __bf16 bf16x8 __attribute__((ext_vector_type(8)));

#define AS1 __attribute__((address_space(1)))
#define AS3 __attribute__((address_space(3)))

__device__ __forceinline__ float bf2f(u16 h) {
  return __uint_as_float(((unsigned)h) << 16);
}
__device__ __forceinline__ u16 f2bf(float f) {
  unsigned u = __float_as_uint(f);
  unsigned r = (u + 0x7FFFu + ((u >> 16) & 1u)) >> 16;
  return (u16)r;
}
__device__ __forceinline__ void gload16(const u16* g, u16* l) {
  __builtin_amdgcn_global_load_lds((const AS1 void*)g, (AS3 void*)l, 16, 0, 0);
}

// ---------------------------------------------------------------- transpose
// out[C,R] = bf16(in[R,C]^T), in fp32; R,C multiples of 32
__global__ void transpose_k(const float* __restrict__ in, u16* __restrict__ out,
                            int R, int C) {
  __shared__ u16 t[32][33];
  int c0 = blockIdx.x * 32, r0 = blockIdx.y * 32;
  int tx = threadIdx.x & 31, ty = threadIdx.x >> 5; // 32 x 8
  for (int i = 0; i < 32; i += 8)
    t[ty + i][tx] = f2bf(in[(size_t)(r0 + ty + i) * C + c0 + tx]);
  __syncthreads();
  for (int i = 0; i < 32; i += 8)
    out[(size_t)(c0 + ty + i) * R + r0 + tx] = t[tx][ty + i];
}

// four 768x768 weight transposes in one launch (z selects)
__global__ void transpose4_k(const float* __restrict__ s0, const float* __restrict__ s1,
                             const float* __restrict__ s2, const float* __restrict__ s3,
                             u16* __restrict__ d0, u16* __restrict__ d1,
                             u16* __restrict__ d2, u16* __restrict__ d3) {
  __shared__ u16 t[32][33];
  const float* in = (blockIdx.z == 0) ? s0 : (blockIdx.z == 1) ? s1
                    : (blockIdx.z == 2) ? s2 : s3;
  u16* out = (blockIdx.z == 0) ? d0 : (blockIdx.z == 1) ? d1
             : (blockIdx.z == 2) ? d2 : d3;
  int c0 = blockIdx.x * 32, r0 = blockIdx.y * 32;
  int tx = threadIdx.x & 31, ty = threadIdx.x >> 5;
  for (int i = 0; i < 32; i += 8)
    t[ty + i][tx] = f2bf(in[(size_t)(r0 + ty + i) * 768 + c0 + tx]);
  __syncthreads();
  for (int i = 0; i < 32; i += 8)
    out[(size_t)(c0 + ty + i) * 768 + r0 + tx] = t[tx][ty + i];
}

// pack bq|bk|bv -> bqkv[2304] fp32
__global__ void pack3_k(const float* __restrict__ a, const float* __restrict__ b,
                        const float* __restrict__ c, float* __restrict__ out) {
  int i = blockIdx.x * 256 + threadIdx.x;
  float v = (i < 768) ? a[i] : (i < 1536) ? b[i - 768] : c[i - 1536];
  out[i] = v;
}

// V columns of fused qkv [16384, 2304] -> VT [bh][96][1024]
#define QLD 2304
__global__ void vtrans_k(const u16* __restrict__ qkv, u16* __restrict__ vt) {
  __shared__ u16 t[32][33];
  int bh = blockIdx.z, b = bh >> 3, h = bh & 7;
  int n0 = blockIdx.y * 32, d0 = blockIdx.x * 32;
  int tx = threadIdx.x & 31, ty = threadIdx.x >> 5;
  const u16* src = qkv + (size_t)(b * 1024) * QLD + 1536 + h * 96;
  for (int i = 0; i < 32; i += 8)
    t[ty + i][tx] = src[(size_t)(n0 + ty + i) * QLD + d0 + tx];
  __syncthreads();
  u16* dst = vt + ((size_t)bh * 96 + d0) * 1024 + n0;
  for (int i = 0; i < 32; i += 8)
    dst[(size_t)(ty + i) * 1024 + tx] = t[tx][ty + i];
}

// ---------------------------------------------------------------- layernorm
// fp32 x -> bf16 out; gamma/beta fp32
__global__ __launch_bounds__(256) void ln_f32_k(const float* __restrict__ x,
                                                const float* __restrict__ gamma,
                                                const float* __restrict__ beta,
                                                u16* __restrict__ out) {
  __shared__ float red[8];
  int row = blockIdx.x, t = threadIdx.x;
  const float* xr = x + (size_t)row * 768;
  float v[3], s = 0.f, s2 = 0.f;
#pragma unroll
  for (int i = 0; i < 3; i++) {
    v[i] = xr[t + i * 256];
    s += v[i]; s2 += v[i] * v[i];
  }
#pragma unroll
  for (int off = 1; off < 64; off <<= 1) {
    s += __shfl_xor(s, off, 64);
    s2 += __shfl_xor(s2, off, 64);
  }
  int w = t >> 6;
  if ((t & 63) == 0) { red[w] = s; red[4 + w] = s2; }
  __syncthreads();
  s = red[0] + red[1] + red[2] + red[3];
  s2 = red[4] + red[5] + red[6] + red[7];
  float mu = s * (1.f / 768.f);
  float var = s2 * (1.f / 768.f) - mu * mu;
  float rs = rsqrtf(var + 1e-5f);
  u16* orow = out + (size_t)row * 768;
#pragma unroll
  for (int i = 0; i < 3; i++) {
    int c = t + i * 256;
    orow[c] = f2bf((v[i] - mu) * rs * gamma[c] + beta[c]);
  }
}

// ---------------------------------------------------------------- GEMM
// EPI 0: C=bf16(A@Bt^T + bias)
// EPI 2: C=bf16(gelu(A@Bt^T + bias))
// EPI 4: C=fp32(A@Bt^T + bias + res_fp32)   (res may alias C 1:1)
// R8: TRIPLE-buffered BK=32 (48KB LDS -> 3 blocks/CU) with prefetch
// distance 2: the tile waited by vmcnt(8) was issued two compute phases
// (~600-800cy) ago, covering A-tile L3/HBM latency (R7's distance-1
// vmcnt(4) only covered ~300cy -> stalled on streaming A loads).
// Fragment-major LDS subtiles (contiguous 1KB wave reads, conflict-free;
// global source pre-permuted per m173). Raw s_barrier, never vmcnt(0) in
// the loop. XCD-aware block swizzle (gridDim.x % 8 == 0).
#define BM 128
#define BN 128
#define BK 32

template <int EPI>
__global__ __launch_bounds__(256, 3) void gemm_bt(
    const u16* __restrict__ A, const u16* __restrict__ Bt,
    const float* __restrict__ bias, const float* __restrict__ res,
    void* __restrict__ Cv, int M, int N, int K, int lda) {
  __shared__ u16 As[3][BM * BK];
  __shared__ u16 Bs[3][BN * BK];
  int tid = threadIdx.x, lane = tid & 63, w = tid >> 6;
  int l15 = lane & 15, quad = lane >> 4;
  int wm = (w >> 1) * 64, wn = (w & 1) * 64;
  // XCD-aware swizzle: f = HW linear block id (x fastest)
  int GX = gridDim.x;
  int f = blockIdx.y * GX + blockIdx.x;
  int mpx = GX >> 3;                     // m-tiles per XCD
  int xcd = f & 7, idx = f >> 3;
  int m0 = (xcd * mpx + (idx % mpx)) * BM;
  int n0 = (idx / mpx) * BN;
  int NT = K / BK;
  // staging: chunk c = w*2+i is subtile c (rows c*16..+15, cols 0..31, 1KB)
  // lane covers row c*16 + l15, cols quad*8..+7 (matches MFMA read order)
  // prologue: stage tiles 0 and 1
#pragma unroll
  for (int pt = 0; pt < 2; pt++) {
#pragma unroll
    for (int i = 0; i < 2; i++) {
      int c = w * 2 + i;
      int r = c * 16 + l15, col = pt * BK + quad * 8;
      gload16(A + (size_t)(m0 + r) * lda + col, As[pt] + c * 512);
      gload16(Bt + (size_t)(n0 + r) * K + col, Bs[pt] + c * 512);
    }
  }
  f32x4 acc[4][4] = {};
  for (int t = 0; t < NT; t++) {
    int cur = t % 3, nx = (t + 2) % 3;   // nx == (t-1)%3: freed by barrier
    // barrier 1: everyone finished compute t-1 (the readers of buf nx)
    __builtin_amdgcn_s_barrier();
    int k0 = (t + 2 < NT) ? (t + 2) * BK : 0;  // wraparound: harmless restage
#pragma unroll
    for (int i = 0; i < 2; i++) {
      int c = w * 2 + i;
      int r = c * 16 + l15, col = quad * 8;
      gload16(A + (size_t)(m0 + r) * lda + k0 + col, As[nx] + c * 512);
      gload16(Bt + (size_t)(n0 + r) * K + k0 + col, Bs[nx] + c * 512);
    }
    // 12 outstanding; wait the oldest 4 (tile t, issued 2 iters ago)
    asm volatile("s_waitcnt vmcnt(8)" ::: "memory");
    // barrier 2: tile t ready for every thread
    __builtin_amdgcn_s_barrier();
    const u16* ab = As[cur];
    const u16* bb = Bs[cur];
    bf16x8 af[4], bfv[4];
#pragma unroll
    for (int i = 0; i < 4; i++) {
      af[i] = *(const bf16x8*)(ab + ((w >> 1) * 4 + i) * 512 + lane * 8);
      bfv[i] = *(const bf16x8*)(bb + ((w & 1) * 4 + i) * 512 + lane * 8);
    }
#pragma unroll
    for (int mt = 0; mt < 4; mt++)
#pragma unroll
      for (int nt = 0; nt < 4; nt++)
        acc[mt][nt] = __builtin_amdgcn_mfma_f32_16x16x32_bf16(
            af[mt], bfv[nt], acc[mt][nt], 0, 0, 0);
  }
  // drain dangling wraparound prefetches
  asm volatile("s_waitcnt vmcnt(0)" ::: "memory");
  // epilogue: C/D layout col=lane&15, row=quad*4+reg (m89/m91-verified)
#pragma unroll
  for (int nt = 0; nt < 4; nt++) {
    int col = n0 + wn + nt * 16 + l15;
    float bv = bias[col];
#pragma unroll
    for (int mt = 0; mt < 4; mt++) {
      int row = m0 + wm + mt * 16 + quad * 4;
#pragma unroll
      for (int r = 0; r < 4; r++) {
        float v = acc[mt][nt][r] + bv;
        size_t idx2 = (size_t)(row + r) * N + col;
        if (EPI == 4) {
          v += res[idx2];
          ((float*)Cv)[idx2] = v;
        } else {
          if (EPI == 2) v = 0.5f * v * (1.0f + erff(v * 0.70710678118654752f));
          ((u16*)Cv)[idx2] = f2bf(v);
        }
      }
    }
  }
}

// ---------------------------------------------------------------- attention
// flash-style on fused qkv [16384,2304] (q cols 0..767, k cols 768..1535);
// vt: [bh][96][1024]; OUTPUT to separate dense [16384,768] buffer (R5
// lesson: strided output = 8x write amplification; reads are fine).
// R1: padded LDS strides. R2/R3: 2-phase schedule, double-buffered ks/vts,
// wraparound reg prefetch, ONE barrier/kt. R4: XCD swizzle; per-lane
// partial li; scale folded into exp args.
#define QSS 104
#define VSS 72
#define PSS 72
__global__ __launch_bounds__(256, 2) void attn_k(const u16* __restrict__ qkv,
                                                 const u16* __restrict__ vt,
                                                 u16* __restrict__ o) {
  __shared__ u16 qs[64 * QSS];
  __shared__ u16 ks[2][64 * QSS];
  __shared__ u16 vts[2][96 * VSS];
  __shared__ u16 ps[4 * 16 * PSS];
  int tid = threadIdx.x, lane = tid & 63, w = tid >> 6;
  int l15 = lane & 15, quad = lane >> 4;
  // XCD swizzle: grid (16,128); give each XCD 16 contiguous bh (all qt)
  int f = blockIdx.y * 16 + blockIdx.x;
  int xcd = f & 7, idx = f >> 3;        // idx in [0,256)
  int bh = xcd * 16 + (idx & 15);
  int qt = idx >> 4;
  int b = bh >> 3, h = bh & 7;
  const u16* qbase = qkv + (size_t)(b * 1024 + qt * 64) * QLD + h * 96;
  const u16* kbase = qkv + (size_t)(b * 1024) * QLD + 768 + h * 96;
  const u16* vtbase = vt + (size_t)bh * 96 * 1024;
  // per-thread staging coordinates (3 chunks each for K and VT)
  int kr[3], ko[3], vr[3], vo[3];
#pragma unroll
  for (int i = 0; i < 3; i++) {
    int c = tid + i * 256;
    kr[i] = c / 12; ko[i] = (c % 12) * 8;
    vr[i] = c >> 3; vo[i] = (c & 7) * 8;
  }
  // Q stage
#pragma unroll
  for (int i = 0; i < 3; i++)
    *(uint4*)(qs + kr[i] * QSS + ko[i]) =
        *(const uint4*)(qbase + (size_t)kr[i] * QLD + ko[i]);
  // prologue: stage tile 0
  uint4 kreg[3], vreg[3];
#pragma unroll
  for (int i = 0; i < 3; i++) {
    kreg[i] = *(const uint4*)(kbase + (size_t)kr[i] * QLD + ko[i]);
    vreg[i] = *(const uint4*)(vtbase + (size_t)vr[i] * 1024 + vo[i]);
  }
#pragma unroll
  for (int i = 0; i < 3; i++) {
    *(uint4*)(ks[0] + kr[i] * QSS + ko[i]) = kreg[i];
    *(uint4*)(vts[0] + vr[i] * VSS + vo[i]) = vreg[i];
  }
  __syncthreads();

  float mi[4], li[4];   // mi: RAW-domain running max; li: per-lane PARTIAL sum
#pragma unroll
  for (int r = 0; r < 4; r++) { mi[r] = -1e30f; li[r] = 0.f; }
  f32x4 oacc[6] = {};
  const float scale = 0.10206207261596577f; // 1/sqrt(96)
  for (int kt = 0; kt < 16; kt++) {
    int cur = kt & 1, nxt = cur ^ 1;
    int ktn = (kt + 1) & 15;  // wraparound: last iter re-fetches tile 0
    // issue prefetch of next tile (completion waited only at the ds_write
    // block after PV — ~2000cy of compute hides the latency)
#pragma unroll
    for (int i = 0; i < 3; i++) {
      kreg[i] = *(const uint4*)(kbase + (size_t)(ktn * 64 + kr[i]) * QLD + ko[i]);
      vreg[i] = *(const uint4*)(vtbase + (size_t)vr[i] * 1024 + ktn * 64 + vo[i]);
    }
    // QK^T on current buffer
    f32x4 s[4] = {};
#pragma unroll
    for (int kk = 0; kk < 3; kk++) {
      bf16x8 a = *(const bf16x8*)(qs + (w * 16 + l15) * QSS + kk * 32 + quad * 8);
#pragma unroll
      for (int nt = 0; nt < 4; nt++) {
        bf16x8 bb =
            *(const bf16x8*)(ks[cur] + (nt * 16 + l15) * QSS + kk * 32 + quad * 8);
        s[nt] = __builtin_amdgcn_mfma_f32_16x16x32_bf16(a, bb, s[nt], 0, 0, 0);
      }
    }
    // online softmax (4 rows per lane-group via quad); raw-domain max
#pragma unroll
    for (int r = 0; r < 4; r++) {
      float sv[4], mx = -1e30f;
#pragma unroll
      for (int nt = 0; nt < 4; nt++) {
        sv[nt] = s[nt][r];
        mx = fmaxf(mx, sv[nt]);
      }
#pragma unroll
      for (int off = 1; off < 16; off <<= 1) mx = fmaxf(mx, __shfl_xor(mx, off, 16));
      float mnew = fmaxf(mi[r], mx);
      float alpha = __expf((mi[r] - mnew) * scale);
      float rs = 0.f;
#pragma unroll
      for (int nt = 0; nt < 4; nt++) {
        sv[nt] = __expf((sv[nt] - mnew) * scale);
        rs += sv[nt];
      }
      li[r] = li[r] * alpha + rs;   // per-lane partial; reduced after loop
      mi[r] = mnew;
#pragma unroll
      for (int ht = 0; ht < 6; ht++) oacc[ht][r] *= alpha;
      int prow = quad * 4 + r;
#pragma unroll
      for (int nt = 0; nt < 4; nt++)
        ps[w * 16 * PSS + prow * PSS + nt * 16 + l15] = f2bf(sv[nt]);
    }
    // ps is wave-private: order write->read within the wave, no barrier
    asm volatile("s_waitcnt lgkmcnt(0)" ::: "memory");
    // PV on current buffer
#pragma unroll
    for (int kk = 0; kk < 2; kk++) {
      bf16x8 a = *(const bf16x8*)(ps + w * 16 * PSS + l15 * PSS + kk * 32 + quad * 8);
#pragma unroll
      for (int ht = 0; ht < 6; ht++) {
        bf16x8 bb =
            *(const bf16x8*)(vts[cur] + (ht * 16 + l15) * VSS + kk * 32 + quad * 8);
        oacc[ht] = __builtin_amdgcn_mfma_f32_16x16x32_bf16(a, bb, oacc[ht], 0, 0, 0);
      }
    }
    // write prefetched tile into next buffer (freed by the barrier that
    // ended iteration kt-1), then the single per-iteration barrier
#pragma unroll
    for (int i = 0; i < 3; i++) {
      *(uint4*)(ks[nxt] + kr[i] * QSS + ko[i]) = kreg[i];
      *(uint4*)(vts[nxt] + vr[i] * VSS + vo[i]) = vreg[i];
    }
    __syncthreads();
  }
  // reduce per-lane partial li across the 16-lane row group (once)
#pragma unroll
  for (int r = 0; r < 4; r++)
#pragma unroll
    for (int off = 1; off < 16; off <<= 1) li[r] += __shfl_xor(li[r], off, 16);
  u16* obase = o + (size_t)(b * 1024 + qt * 64 + w * 16) * 768 + h * 96;
#pragma unroll
  for (int r = 0; r < 4; r++) {
    float inv = 1.0f / li[r];
    int row = quad * 4 + r;
#pragma unroll
    for (int ht = 0; ht < 6; ht++)
      obase[(size_t)row * 768 + ht * 16 + l15] = f2bf(oacc[ht][r] * inv);
  }
}

// ---------------------------------------------------------------- launch
// d_out is FP32 (reference output dtype). Timeline reuse of d_out:
//   vtrans writes VT (bf16, 25.2MB) into d_out -> attn reads it ->
//   Wo-GEMM overwrites d_out with y1 (VT dead) -> FFN2 reads res=y1 and
//   writes out 1:1-aliased (safe: each (row,col) read-then-written by
//   exactly one thread).
// ws: weights 14.2MB + bqkv + hb 25.2MB + qkvb 75.5MB ~= 115MB (proven).
// hb timeline: h -> (QKV done, dead) -> attn-out -> (Wo done, dead) -> h2.
// qkvb timeline: qkv (+v cols dead after vtrans) -> (Wo done) -> f-chunks.
extern "C" void kernel_launch(void* const* d_in, const int* in_sizes, int n_in,
                              void* d_out, int out_size, void* d_ws,
                              size_t ws_size, hipStream_t stream) {
  const float* x = (const float*)d_in[0];
  const float* gamma = (const float*)d_in[1];
  const float* beta = (const float*)d_in[2];
  const float* Wq = (const float*)d_in[3];
  const float* bq = (const float*)d_in[4];
  const float* Wk = (const float*)d_in[5];
  const float* bk = (const float*)d_in[6];
  const float* Wv = (const float*)d_in[7];
  const float* bv = (const float*)d_in[8];
  const float* Wo = (const float*)d_in[9];
  const float* bo = (const float*)d_in[10];
  const float* W1 = (const float*)d_in[11];
  const float* b1 = (const float*)d_in[12];
  const float* W2 = (const float*)d_in[13];
  const float* b2 = (const float*)d_in[14];
  float* out = (float*)d_out;

  char* ws = (char*)d_ws;
  size_t off = 0;
  auto alloc = [&](size_t elems) {
    u16* p = (u16*)(ws + off);
    off += elems * sizeof(u16);
    return p;
  };
  u16* WqT = alloc(768 * 768);   // WqT|WkT|WvT adjacent = fused [2304,768]
  u16* WkT = alloc(768 * 768);
  u16* WvT = alloc(768 * 768);
  u16* WoT = alloc(768 * 768);
  u16* W1T = alloc((size_t)768 * 3072);    // [3072,768]
  u16* W2T = alloc((size_t)3072 * 768);    // [768,3072]
  float* bqkv = (float*)(ws + off); off += 2304 * sizeof(float);
  u16* hb = alloc((size_t)16384 * 768);    // h -> attn_out -> h2
  u16* qkvb = alloc((size_t)16384 * 2304); // qkv -> f-chunks
  u16* vtb = (u16*)d_out;                  // VT lives in d_out until Wo

  // weight transposes fp32 -> bf16 [N,K]
  transpose4_k<<<dim3(24, 24, 4), 256, 0, stream>>>(Wq, Wk, Wv, Wo,
                                                    WqT, WkT, WvT, WoT);
  transpose_k<<<dim3(96, 24), 256, 0, stream>>>(W1, W1T, 768, 3072);
  transpose_k<<<dim3(24, 96), 256, 0, stream>>>(W2, W2T, 3072, 768);
  pack3_k<<<9, 256, 0, stream>>>(bq, bk, bv, bqkv);

  // LN1: x(fp32) -> h(bf16)
  ln_f32_k<<<16384, 256, 0, stream>>>(x, gamma, beta, hb);
  // fused QKV projection: [16384,768] @ [2304,768]^T -> qkvb [16384,2304]
  gemm_bt<0><<<dim3(128, 18), 256, 0, stream>>>(hb, WqT, bqkv, nullptr, qkvb,
                                                16384, 2304, 768, 768);
  // V cols -> VT [bh][96][1024] into d_out
  vtrans_k<<<dim3(3, 32, 128), 256, 0, stream>>>(qkvb, vtb);
  // attention: q,k from qkvb + VT from d_out -> dense attn-out in hb
  attn_k<<<dim3(16, 128), 256, 0, stream>>>(qkvb, vtb, hb);
  // y1(fp32, in d_out) = attn_out @ Wo + bo + x  (overwrites VT - dead)
  gemm_bt<4><<<dim3(128, 6), 256, 0, stream>>>(hb, WoT, bo, x, out,
                                               16384, 768, 768, 768);
  // h2 = LN(y1) -> hb (attn-out dead)
  ln_f32_k<<<16384, 256, 0, stream>>>(out, gamma, beta, hb);
  // FFN in 2 M-chunks of 8192 rows; f-chunk [8192,3072] bf16 fits qkvb
  for (int c = 0; c < 2; c++) {
    const u16* h2c = hb + (size_t)c * 8192 * 768;
    const float* y1c = out + (size_t)c * 8192 * 768;
    float* outc = out + (size_t)c * 8192 * 768;
    gemm_bt<2><<<dim3(64, 24), 256, 0, stream>>>(h2c, W1T, b1, nullptr, qkvb,
                                                 8192, 3072, 768, 768);
    gemm_bt<4><<<dim3(64, 6), 256, 0, stream>>>(qkvb, W2T, b2, y1c, outc,
                                                8192, 768, 3072, 3072);
  }
}